// Round 3
// baseline (1464.100 us; speedup 1.0000x reference)
//
#include <hip/hip_runtime.h>
#include <hip/hip_bf16.h>

#define NN 60000
#define NE 600000
#define DD 128
#define NTOT (NE + NN)

// ---- degree (edges only; +1 self-loop folded in later) ----
__global__ __launch_bounds__(256) void deg_kernel(const int* __restrict__ dst, int* __restrict__ deg) {
    int e = blockIdx.x * 256 + threadIdx.x;
    if (e < NE) atomicAdd(&deg[dst[e]], 1);
}

__global__ __launch_bounds__(256) void dinv_kernel(const int* __restrict__ deg, float* __restrict__ dinv) {
    int i = blockIdx.x * 256 + threadIdx.x;
    if (i < NN) dinv[i] = rsqrtf((float)(deg[i] + 1));
}

// ---- exclusive scan of (deg[i]+1) -> rowptr[0..NN], single block of 1024 ----
__global__ __launch_bounds__(1024) void scan_kernel(const int* __restrict__ deg, int* __restrict__ rowptr) {
    __shared__ int lds[1024];
    const int CH = (NN + 1023) / 1024;  // 59
    int t = threadIdx.x;
    int lo = t * CH, hi = min(lo + CH, NN);
    int s = 0;
    for (int i = lo; i < hi; i++) s += deg[i] + 1;
    lds[t] = s;
    __syncthreads();
    for (int off = 1; off < 1024; off <<= 1) {
        int v = (t >= off) ? lds[t - off] : 0;
        __syncthreads();
        lds[t] += v;
        __syncthreads();
    }
    int run = (t > 0) ? lds[t - 1] : 0;  // exclusive prefix of this chunk
    for (int i = lo; i < hi; i++) {
        rowptr[i] = run;
        run += deg[i] + 1;
    }
    if (t == 0) rowptr[NN] = NTOT;
}

// ---- CSR fill: items [0,NE) real edges, [NE,NTOT) self-loops ----
__global__ __launch_bounds__(256) void fill_kernel(const int* __restrict__ src, const int* __restrict__ dst,
                                                   const int* __restrict__ rowptr, int* __restrict__ cursor,
                                                   const float* __restrict__ dinv,
                                                   int* __restrict__ csr_src, float* __restrict__ csr_coef) {
    int e = blockIdx.x * 256 + threadIdx.x;
    if (e >= NTOT) return;
    int s, t;
    if (e < NE) { s = src[e]; t = dst[e]; }
    else { s = t = e - NE; }
    int pos = atomicAdd(&cursor[t], 1);
    int i = rowptr[t] + pos;
    csr_src[i] = s;
    csr_coef[i] = dinv[s] * dinv[t];
}

// ---- GEMM: C[NN x 128] = A[NN x 128] @ W[128 x 128] ----
// 64-row tile, k-chunks of 32. LDS = 8KB(A) + 16KB(W). Thread: 8 rows x 4 cols.
__global__ __launch_bounds__(256, 4) void gemm_kernel(const float* __restrict__ A,
                                                      const float* __restrict__ W,
                                                      float* __restrict__ C) {
    __shared__ float As[64][32];   // 8KB
    __shared__ float Ws[32][DD];   // 16KB
    int tid = threadIdx.x;
    int tx = tid & 31;   // col group: cols 4*tx .. 4*tx+3
    int ty = tid >> 5;   // row group: rows ty*8 .. ty*8+7
    int rbase = blockIdx.x * 64;

    float acc[8][4];
#pragma unroll
    for (int r = 0; r < 8; r++)
#pragma unroll
        for (int c = 0; c < 4; c++) acc[r][c] = 0.f;

    for (int k0 = 0; k0 < DD; k0 += 32) {
        // stage A: 64 rows x 32 k = 512 float4, 2 per thread
#pragma unroll
        for (int u = tid; u < 512; u += 256) {
            int r = u >> 3, c = u & 7;
            int rr = min(rbase + r, NN - 1);  // clamp (60000 % 64 == 32)
            float4 v = *(const float4*)&A[(size_t)rr * DD + k0 + 4 * c];
            *(float4*)&As[r][4 * c] = v;
        }
        // stage W: 32 k x 128 cols = 1024 float4, 4 per thread
#pragma unroll
        for (int u = tid; u < 1024; u += 256) {
            int kk = u >> 5, c = u & 31;
            *(float4*)&Ws[kk][4 * c] = *(const float4*)&W[(size_t)(k0 + kk) * DD + 4 * c];
        }
        __syncthreads();

        for (int kk = 0; kk < 32; kk += 4) {
            float4 wv0 = *(float4*)&Ws[kk + 0][4 * tx];
            float4 wv1 = *(float4*)&Ws[kk + 1][4 * tx];
            float4 wv2 = *(float4*)&Ws[kk + 2][4 * tx];
            float4 wv3 = *(float4*)&Ws[kk + 3][4 * tx];
#pragma unroll
            for (int r = 0; r < 8; r++) {
                float4 av = *(float4*)&As[ty * 8 + r][kk];
                acc[r][0] += av.x * wv0.x + av.y * wv1.x + av.z * wv2.x + av.w * wv3.x;
                acc[r][1] += av.x * wv0.y + av.y * wv1.y + av.z * wv2.y + av.w * wv3.y;
                acc[r][2] += av.x * wv0.z + av.y * wv1.z + av.z * wv2.z + av.w * wv3.z;
                acc[r][3] += av.x * wv0.w + av.y * wv1.w + av.z * wv2.w + av.w * wv3.w;
            }
        }
        __syncthreads();
    }
#pragma unroll
    for (int r = 0; r < 8; r++) {
        int row = rbase + ty * 8 + r;
        if (row < NN) *(float4*)&C[(size_t)row * DD + 4 * tx] =
            make_float4(acc[r][0], acc[r][1], acc[r][2], acc[r][3]);
    }
}

// ---- CSR gather-aggregate: one wave per node, 2 features per lane, no atomics ----
__global__ __launch_bounds__(256) void gather_kernel(const float* __restrict__ xw,
                                                     const int* __restrict__ rowptr,
                                                     const int* __restrict__ csr_src,
                                                     const float* __restrict__ csr_coef,
                                                     float* __restrict__ agg) {
    int wid = (int)((blockIdx.x * 256 + threadIdx.x) >> 6);
    int l = threadIdx.x & 63;
    if (wid >= NN) return;
    int beg = rowptr[wid], end = rowptr[wid + 1];
    float a0 = 0.f, a1 = 0.f;
    int i = beg;
    for (; i + 2 <= end; i += 2) {
        int s0 = csr_src[i], s1 = csr_src[i + 1];
        float c0 = csr_coef[i], c1 = csr_coef[i + 1];
        const float* r0 = xw + (size_t)s0 * DD;
        const float* r1 = xw + (size_t)s1 * DD;
        float x00 = r0[l], x01 = r0[l + 64];
        float x10 = r1[l], x11 = r1[l + 64];
        a0 += x00 * c0; a1 += x01 * c0;
        a0 += x10 * c1; a1 += x11 * c1;
    }
    if (i < end) {
        int s0 = csr_src[i];
        float c0 = csr_coef[i];
        const float* r0 = xw + (size_t)s0 * DD;
        a0 += r0[l] * c0; a1 += r0[l + 64] * c0;
    }
    agg[(size_t)wid * DD + l] = a0;
    agg[(size_t)wid * DD + 64 + l] = a1;
}

// ---- batchnorm stats: sums[0..127]=sum, sums[128..255]=sumsq ----
__global__ __launch_bounds__(256) void bnstat_kernel(const float* __restrict__ h, float* __restrict__ sums) {
    int d = threadIdx.x & 127;
    int rg = threadIdx.x >> 7;
    int r0 = blockIdx.x * 256 + rg;
    float s = 0.f, q = 0.f;
    for (int i = 0; i < 128; i++) {
        int r = r0 + 2 * i;
        if (r < NN) {
            float v = h[(size_t)r * DD + d];
            s += v;
            q += v * v;
        }
    }
    __shared__ float ls[256], lq[256];
    ls[threadIdx.x] = s;
    lq[threadIdx.x] = q;
    __syncthreads();
    if (threadIdx.x < 128) {
        s = ls[threadIdx.x] + ls[threadIdx.x + 128];
        q = lq[threadIdx.x] + lq[threadIdx.x + 128];
        atomicAdd(&sums[d], s);
        atomicAdd(&sums[128 + d], q);
    }
}

// ---- normalize + affine + leaky-relu. GCN bias b omitted: cancels in BN. ----
__global__ __launch_bounds__(256) void bnapply_kernel(const float* __restrict__ h,
                                                      const float* __restrict__ sums,
                                                      const float* __restrict__ g,
                                                      const float* __restrict__ be,
                                                      float* __restrict__ out,
                                                      int act) {
    int idx = blockIdx.x * 256 + threadIdx.x;
    if (idx >= NN * DD) return;
    int d = idx & 127;
    const float invN = 1.0f / (float)NN;
    float mu = sums[d] * invN;
    float var = sums[128 + d] * invN - mu * mu;
    float inv = rsqrtf(var + 1e-5f);
    float v = (h[idx] - mu) * inv * g[d] + be[d];
    if (act) v = (v >= 0.f) ? v : 0.01f * v;
    out[idx] = v;
}

extern "C" void kernel_launch(void* const* d_in, const int* in_sizes, int n_in,
                              void* d_out, int out_size, void* d_ws, size_t ws_size,
                              hipStream_t stream) {
    const float* x = (const float*)d_in[0];
    const int* ei = (const int*)d_in[1];
    const int* srcp = ei;
    const int* dstp = ei + NE;
    const float* w[3]  = {(const float*)d_in[2], (const float*)d_in[6],  (const float*)d_in[10]};
    const float* g[3]  = {(const float*)d_in[4], (const float*)d_in[8],  (const float*)d_in[12]};
    const float* be[3] = {(const float*)d_in[5], (const float*)d_in[9],  (const float*)d_in[13]};

    // workspace layout (~68 MB)
    float* bufA = (float*)d_ws;                        // xw  [NN*DD]
    float* bufB = bufA + (size_t)NN * DD;              // h / agg [NN*DD]
    int* deg    = (int*)(bufB + (size_t)NN * DD);      // [NN]
    int* cursor = deg + NN;                            // [NN]
    int* rowptr = cursor + NN;                         // [NN+1]
    float* dinv = (float*)(rowptr + NN + 1);           // [NN]
    float* sums = dinv + NN;                           // [256]
    int* csr_src = (int*)(sums + 256);                 // [NTOT]
    float* csr_coef = (float*)(csr_src + NTOT);        // [NTOT]
    float* out = (float*)d_out;

    // ---- CSR build (once; edge_index constant across layers) ----
    hipMemsetAsync(deg, 0, NN * sizeof(int), stream);
    hipMemsetAsync(cursor, 0, NN * sizeof(int), stream);
    deg_kernel<<<(NE + 255) / 256, 256, 0, stream>>>(dstp, deg);
    dinv_kernel<<<(NN + 255) / 256, 256, 0, stream>>>(deg, dinv);
    scan_kernel<<<1, 1024, 0, stream>>>(deg, rowptr);
    fill_kernel<<<(NTOT + 255) / 256, 256, 0, stream>>>(srcp, dstp, rowptr, cursor, dinv, csr_src, csr_coef);

    for (int L = 0; L < 3; ++L) {
        const float* in = (L == 0) ? x : bufB;
        gemm_kernel<<<(NN + 63) / 64, 256, 0, stream>>>(in, w[L], bufA);
        hipMemsetAsync(sums, 0, 256 * sizeof(float), stream);
        gather_kernel<<<(NN + 3) / 4, 256, 0, stream>>>(bufA, rowptr, csr_src, csr_coef, bufB);
        bnstat_kernel<<<(NN + 255) / 256, 256, 0, stream>>>(bufB, sums);
        int last = (L == 2);
        bnapply_kernel<<<(NN * DD + 255) / 256, 256, 0, stream>>>(
            bufB, sums, g[L], be[L], last ? out : bufB, last ? 0 : 1);
    }
}

// Round 4
// 771.903 us; speedup vs baseline: 1.8967x; 1.8967x over previous
//
#include <hip/hip_runtime.h>
#include <hip/hip_bf16.h>

#define NN 60000
#define NE 600000
#define DD 128
#define NTOT (NE + NN)

// ---- degree (edges only; +1 self-loop folded in later) ----
__global__ __launch_bounds__(256) void deg_kernel(const int* __restrict__ dst, int* __restrict__ deg) {
    int e = blockIdx.x * 256 + threadIdx.x;
    if (e < NE) atomicAdd(&deg[dst[e]], 1);
}

__global__ __launch_bounds__(256) void dinv_kernel(const int* __restrict__ deg, float* __restrict__ dinv) {
    int i = blockIdx.x * 256 + threadIdx.x;
    if (i < NN) dinv[i] = rsqrtf((float)(deg[i] + 1));
}

// ---- exclusive scan of (deg[i]+1) -> rowptr[0..NN], single block of 1024 ----
__global__ __launch_bounds__(1024) void scan_kernel(const int* __restrict__ deg, int* __restrict__ rowptr) {
    __shared__ int lds[1024];
    const int CH = (NN + 1023) / 1024;  // 59
    int t = threadIdx.x;
    int lo = t * CH, hi = min(lo + CH, NN);
    int s = 0;
    for (int i = lo; i < hi; i++) s += deg[i] + 1;
    lds[t] = s;
    __syncthreads();
    for (int off = 1; off < 1024; off <<= 1) {
        int v = (t >= off) ? lds[t - off] : 0;
        __syncthreads();
        lds[t] += v;
        __syncthreads();
    }
    int run = (t > 0) ? lds[t - 1] : 0;  // exclusive prefix of this chunk
    for (int i = lo; i < hi; i++) {
        rowptr[i] = run;
        run += deg[i] + 1;
    }
    if (t == 0) rowptr[NN] = NTOT;
}

// ---- CSR fill: items [0,NE) real edges, [NE,NTOT) self-loops ----
__global__ __launch_bounds__(256) void fill_kernel(const int* __restrict__ src, const int* __restrict__ dst,
                                                   const int* __restrict__ rowptr, int* __restrict__ cursor,
                                                   const float* __restrict__ dinv,
                                                   int* __restrict__ csr_src, float* __restrict__ csr_coef) {
    int e = blockIdx.x * 256 + threadIdx.x;
    if (e >= NTOT) return;
    int s, t;
    if (e < NE) { s = src[e]; t = dst[e]; }
    else { s = t = e - NE; }
    int pos = atomicAdd(&cursor[t], 1);
    int i = rowptr[t] + pos;
    csr_src[i] = s;
    csr_coef[i] = dinv[s] * dinv[t];
}

// ---- GEMM: C[NN x 128] = A[NN x 128] @ W[128 x 128] ----
// 64-row tile, k-chunks of 32. LDS = 8KB(A) + 16KB(W). Thread: 8 rows x 4 cols.
// NOTE: no waves/EU hint — __launch_bounds__(256,4) made LLVM target the
// 8-wave/EU 64-VGPR cap and spill acc to scratch (1.05 GiB HBM traffic, R3).
__global__ __launch_bounds__(256) void gemm_kernel(const float* __restrict__ A,
                                                   const float* __restrict__ W,
                                                   float* __restrict__ C) {
    __shared__ float As[64][32];   // 8KB
    __shared__ float Ws[32][DD];   // 16KB
    int tid = threadIdx.x;
    int tx = tid & 31;   // col group: cols 4*tx .. 4*tx+3
    int ty = tid >> 5;   // row group: rows ty*8 .. ty*8+7
    int rbase = blockIdx.x * 64;

    float acc[8][4];
#pragma unroll
    for (int r = 0; r < 8; r++)
#pragma unroll
        for (int c = 0; c < 4; c++) acc[r][c] = 0.f;

    for (int k0 = 0; k0 < DD; k0 += 32) {
        // stage A: 64 rows x 32 k = 512 float4, 2 per thread
#pragma unroll
        for (int u = tid; u < 512; u += 256) {
            int r = u >> 3, c = u & 7;
            int rr = min(rbase + r, NN - 1);  // clamp (60000 % 64 == 32)
            float4 v = *(const float4*)&A[(size_t)rr * DD + k0 + 4 * c];
            *(float4*)&As[r][4 * c] = v;
        }
        // stage W: 32 k x 128 cols = 1024 float4, 4 per thread
#pragma unroll
        for (int u = tid; u < 1024; u += 256) {
            int kk = u >> 5, c = u & 31;
            *(float4*)&Ws[kk][4 * c] = *(const float4*)&W[(size_t)(k0 + kk) * DD + 4 * c];
        }
        __syncthreads();

        for (int kk = 0; kk < 32; kk += 4) {
            float4 wv0 = *(float4*)&Ws[kk + 0][4 * tx];
            float4 wv1 = *(float4*)&Ws[kk + 1][4 * tx];
            float4 wv2 = *(float4*)&Ws[kk + 2][4 * tx];
            float4 wv3 = *(float4*)&Ws[kk + 3][4 * tx];
#pragma unroll
            for (int r = 0; r < 8; r++) {
                float4 av = *(float4*)&As[ty * 8 + r][kk];
                acc[r][0] += av.x * wv0.x + av.y * wv1.x + av.z * wv2.x + av.w * wv3.x;
                acc[r][1] += av.x * wv0.y + av.y * wv1.y + av.z * wv2.y + av.w * wv3.y;
                acc[r][2] += av.x * wv0.z + av.y * wv1.z + av.z * wv2.z + av.w * wv3.z;
                acc[r][3] += av.x * wv0.w + av.y * wv1.w + av.z * wv2.w + av.w * wv3.w;
            }
        }
        __syncthreads();
    }
#pragma unroll
    for (int r = 0; r < 8; r++) {
        int row = rbase + ty * 8 + r;
        if (row < NN) *(float4*)&C[(size_t)row * DD + 4 * tx] =
            make_float4(acc[r][0], acc[r][1], acc[r][2], acc[r][3]);
    }
}

// ---- CSR gather-aggregate: one wave per node, 2 features per lane, no atomics ----
__global__ __launch_bounds__(256) void gather_kernel(const float* __restrict__ xw,
                                                     const int* __restrict__ rowptr,
                                                     const int* __restrict__ csr_src,
                                                     const float* __restrict__ csr_coef,
                                                     float* __restrict__ agg) {
    int wid = (int)((blockIdx.x * 256 + threadIdx.x) >> 6);
    int l = threadIdx.x & 63;
    if (wid >= NN) return;
    int beg = rowptr[wid], end = rowptr[wid + 1];
    float a0 = 0.f, a1 = 0.f;
    int i = beg;
    for (; i + 2 <= end; i += 2) {
        int s0 = csr_src[i], s1 = csr_src[i + 1];
        float c0 = csr_coef[i], c1 = csr_coef[i + 1];
        const float* r0 = xw + (size_t)s0 * DD;
        const float* r1 = xw + (size_t)s1 * DD;
        float x00 = r0[l], x01 = r0[l + 64];
        float x10 = r1[l], x11 = r1[l + 64];
        a0 += x00 * c0; a1 += x01 * c0;
        a0 += x10 * c1; a1 += x11 * c1;
    }
    if (i < end) {
        int s0 = csr_src[i];
        float c0 = csr_coef[i];
        const float* r0 = xw + (size_t)s0 * DD;
        a0 += r0[l] * c0; a1 += r0[l + 64] * c0;
    }
    agg[(size_t)wid * DD + l] = a0;
    agg[(size_t)wid * DD + 64 + l] = a1;
}

// ---- batchnorm stats: sums[0..127]=sum, sums[128..255]=sumsq ----
__global__ __launch_bounds__(256) void bnstat_kernel(const float* __restrict__ h, float* __restrict__ sums) {
    int d = threadIdx.x & 127;
    int rg = threadIdx.x >> 7;
    int r0 = blockIdx.x * 256 + rg;
    float s = 0.f, q = 0.f;
    for (int i = 0; i < 128; i++) {
        int r = r0 + 2 * i;
        if (r < NN) {
            float v = h[(size_t)r * DD + d];
            s += v;
            q += v * v;
        }
    }
    __shared__ float ls[256], lq[256];
    ls[threadIdx.x] = s;
    lq[threadIdx.x] = q;
    __syncthreads();
    if (threadIdx.x < 128) {
        s = ls[threadIdx.x] + ls[threadIdx.x + 128];
        q = lq[threadIdx.x] + lq[threadIdx.x + 128];
        atomicAdd(&sums[d], s);
        atomicAdd(&sums[128 + d], q);
    }
}

// ---- normalize + affine + leaky-relu. GCN bias b omitted: cancels in BN. ----
__global__ __launch_bounds__(256) void bnapply_kernel(const float* __restrict__ h,
                                                      const float* __restrict__ sums,
                                                      const float* __restrict__ g,
                                                      const float* __restrict__ be,
                                                      float* __restrict__ out,
                                                      int act) {
    int idx = blockIdx.x * 256 + threadIdx.x;
    if (idx >= NN * DD) return;
    int d = idx & 127;
    const float invN = 1.0f / (float)NN;
    float mu = sums[d] * invN;
    float var = sums[128 + d] * invN - mu * mu;
    float inv = rsqrtf(var + 1e-5f);
    float v = (h[idx] - mu) * inv * g[d] + be[d];
    if (act) v = (v >= 0.f) ? v : 0.01f * v;
    out[idx] = v;
}

extern "C" void kernel_launch(void* const* d_in, const int* in_sizes, int n_in,
                              void* d_out, int out_size, void* d_ws, size_t ws_size,
                              hipStream_t stream) {
    const float* x = (const float*)d_in[0];
    const int* ei = (const int*)d_in[1];
    const int* srcp = ei;
    const int* dstp = ei + NE;
    const float* w[3]  = {(const float*)d_in[2], (const float*)d_in[6],  (const float*)d_in[10]};
    const float* g[3]  = {(const float*)d_in[4], (const float*)d_in[8],  (const float*)d_in[12]};
    const float* be[3] = {(const float*)d_in[5], (const float*)d_in[9],  (const float*)d_in[13]};

    // workspace layout (~68 MB)
    float* bufA = (float*)d_ws;                        // xw  [NN*DD]
    float* bufB = bufA + (size_t)NN * DD;              // h / agg [NN*DD]
    int* deg    = (int*)(bufB + (size_t)NN * DD);      // [NN]
    int* cursor = deg + NN;                            // [NN]
    int* rowptr = cursor + NN;                         // [NN+1]
    float* dinv = (float*)(rowptr + NN + 1);           // [NN]
    float* sums = dinv + NN;                           // [256]
    int* csr_src = (int*)(sums + 256);                 // [NTOT]
    float* csr_coef = (float*)(csr_src + NTOT);        // [NTOT]
    float* out = (float*)d_out;

    // ---- CSR build (once; edge_index constant across layers) ----
    hipMemsetAsync(deg, 0, NN * sizeof(int), stream);
    hipMemsetAsync(cursor, 0, NN * sizeof(int), stream);
    deg_kernel<<<(NE + 255) / 256, 256, 0, stream>>>(dstp, deg);
    dinv_kernel<<<(NN + 255) / 256, 256, 0, stream>>>(deg, dinv);
    scan_kernel<<<1, 1024, 0, stream>>>(deg, rowptr);
    fill_kernel<<<(NTOT + 255) / 256, 256, 0, stream>>>(srcp, dstp, rowptr, cursor, dinv, csr_src, csr_coef);

    for (int L = 0; L < 3; ++L) {
        const float* in = (L == 0) ? x : bufB;
        gemm_kernel<<<(NN + 63) / 64, 256, 0, stream>>>(in, w[L], bufA);
        hipMemsetAsync(sums, 0, 256 * sizeof(float), stream);
        gather_kernel<<<(NN + 3) / 4, 256, 0, stream>>>(bufA, rowptr, csr_src, csr_coef, bufB);
        bnstat_kernel<<<(NN + 255) / 256, 256, 0, stream>>>(bufB, sums);
        int last = (L == 2);
        bnapply_kernel<<<(NN * DD + 255) / 256, 256, 0, stream>>>(
            bufB, sums, g[L], be[L], last ? out : bufB, last ? 0 : 1);
    }
}

// Round 5
// 662.175 us; speedup vs baseline: 2.2110x; 1.1657x over previous
//
#include <hip/hip_runtime.h>
#include <hip/hip_bf16.h>

#define NN 60000
#define NE 600000
#define DD 128
#define NTOT (NE + NN)
#define NB ((NN + 255) / 256)   // 235 blocks for scan

// ---- degree (edges only; +1 self-loop folded in later) ----
__global__ __launch_bounds__(256) void deg_kernel(const int* __restrict__ dst, int* __restrict__ deg) {
    int e = blockIdx.x * 256 + threadIdx.x;
    if (e < NE) atomicAdd(&deg[dst[e]], 1);
}

__global__ __launch_bounds__(256) void dinv_kernel(const int* __restrict__ deg, float* __restrict__ dinv) {
    int i = blockIdx.x * 256 + threadIdx.x;
    if (i < NN) dinv[i] = rsqrtf((float)(deg[i] + 1));
}

// ---- 3-phase coalesced exclusive scan of (deg[i]+1) -> rowptr ----
__global__ __launch_bounds__(256) void scanA_kernel(const int* __restrict__ deg, int* __restrict__ partials) {
    __shared__ int lds[256];
    int i = blockIdx.x * 256 + threadIdx.x;
    int v = (i < NN) ? deg[i] + 1 : 0;
    lds[threadIdx.x] = v;
    __syncthreads();
    for (int off = 128; off > 0; off >>= 1) {
        if (threadIdx.x < off) lds[threadIdx.x] += lds[threadIdx.x + off];
        __syncthreads();
    }
    if (threadIdx.x == 0) partials[blockIdx.x] = lds[0];
}

__global__ __launch_bounds__(256) void scanB_kernel(const int* __restrict__ partials,
                                                    int* __restrict__ blockoff,
                                                    int* __restrict__ rowptr) {
    __shared__ int lds[256];
    int t = threadIdx.x;
    int v = (t < NB) ? partials[t] : 0;
    lds[t] = v;
    __syncthreads();
    for (int off = 1; off < 256; off <<= 1) {
        int u = (t >= off) ? lds[t - off] : 0;
        __syncthreads();
        lds[t] += u;
        __syncthreads();
    }
    if (t < NB) blockoff[t] = lds[t] - v;  // exclusive
    if (t == 0) rowptr[NN] = NTOT;
}

__global__ __launch_bounds__(256) void scanC_kernel(const int* __restrict__ deg,
                                                    const int* __restrict__ blockoff,
                                                    int* __restrict__ rowptr) {
    __shared__ int lds[256];
    int i = blockIdx.x * 256 + threadIdx.x;
    int t = threadIdx.x;
    int v = (i < NN) ? deg[i] + 1 : 0;
    lds[t] = v;
    __syncthreads();
    for (int off = 1; off < 256; off <<= 1) {
        int u = (t >= off) ? lds[t - off] : 0;
        __syncthreads();
        lds[t] += u;
        __syncthreads();
    }
    if (i < NN) rowptr[i] = blockoff[blockIdx.x] + lds[t] - v;
}

// ---- CSR fill: items [0,NE) real edges, [NE,NTOT) self-loops ----
__global__ __launch_bounds__(256) void fill_kernel(const int* __restrict__ src, const int* __restrict__ dst,
                                                   const int* __restrict__ rowptr, int* __restrict__ cursor,
                                                   const float* __restrict__ dinv,
                                                   int* __restrict__ csr_src, float* __restrict__ csr_coef) {
    int e = blockIdx.x * 256 + threadIdx.x;
    if (e >= NTOT) return;
    int s, t;
    if (e < NE) { s = src[e]; t = dst[e]; }
    else { s = t = e - NE; }
    int pos = atomicAdd(&cursor[t], 1);
    int i = rowptr[t] + pos;
    csr_src[i] = s;
    csr_coef[i] = dinv[s] * dinv[t];
}

// ---- GEMM with fused input-BN+LeakyReLU: C = f(A) @ W ----
// f(a) = leaky(a*scale[k]+shift[k]) if normp else a.  64-row tile, k-chunks of 32.
// NOTE: no waves/EU hint — (256,4) caused 64-VGPR cap + acc spill (R3: 1 GiB traffic).
__global__ __launch_bounds__(256) void gemm_kernel(const float* __restrict__ A,
                                                   const float* __restrict__ W,
                                                   const float* __restrict__ normp,  // [0..127]=scale,[128..255]=shift
                                                   float* __restrict__ C) {
    __shared__ float As[64][32];   // 8KB
    __shared__ float Ws[32][DD];   // 16KB
    int tid = threadIdx.x;
    int tx = tid & 31;
    int ty = tid >> 5;
    int rbase = blockIdx.x * 64;

    float acc[8][4];
#pragma unroll
    for (int r = 0; r < 8; r++)
#pragma unroll
        for (int c = 0; c < 4; c++) acc[r][c] = 0.f;

    for (int k0 = 0; k0 < DD; k0 += 32) {
        // stage A: 64 rows x 32 k = 512 float4, 2 per thread (+ fused norm/act)
#pragma unroll
        for (int u = tid; u < 512; u += 256) {
            int r = u >> 3, c = u & 7;
            int rr = min(rbase + r, NN - 1);  // clamp (60000 % 64 == 32)
            float4 v = *(const float4*)&A[(size_t)rr * DD + k0 + 4 * c];
            if (normp) {
                int d = k0 + 4 * c;
                float4 sc = *(const float4*)&normp[d];
                float4 sh = *(const float4*)&normp[128 + d];
                v.x = fmaf(v.x, sc.x, sh.x); v.y = fmaf(v.y, sc.y, sh.y);
                v.z = fmaf(v.z, sc.z, sh.z); v.w = fmaf(v.w, sc.w, sh.w);
                v.x = (v.x >= 0.f) ? v.x : 0.01f * v.x;
                v.y = (v.y >= 0.f) ? v.y : 0.01f * v.y;
                v.z = (v.z >= 0.f) ? v.z : 0.01f * v.z;
                v.w = (v.w >= 0.f) ? v.w : 0.01f * v.w;
            }
            *(float4*)&As[r][4 * c] = v;
        }
        // stage W: 32 k x 128 cols = 1024 float4, 4 per thread
#pragma unroll
        for (int u = tid; u < 1024; u += 256) {
            int kk = u >> 5, c = u & 31;
            *(float4*)&Ws[kk][4 * c] = *(const float4*)&W[(size_t)(k0 + kk) * DD + 4 * c];
        }
        __syncthreads();

        for (int kk = 0; kk < 32; kk += 4) {
            float4 wv0 = *(float4*)&Ws[kk + 0][4 * tx];
            float4 wv1 = *(float4*)&Ws[kk + 1][4 * tx];
            float4 wv2 = *(float4*)&Ws[kk + 2][4 * tx];
            float4 wv3 = *(float4*)&Ws[kk + 3][4 * tx];
#pragma unroll
            for (int r = 0; r < 8; r++) {
                float4 av = *(float4*)&As[ty * 8 + r][kk];
                acc[r][0] += av.x * wv0.x + av.y * wv1.x + av.z * wv2.x + av.w * wv3.x;
                acc[r][1] += av.x * wv0.y + av.y * wv1.y + av.z * wv2.y + av.w * wv3.y;
                acc[r][2] += av.x * wv0.z + av.y * wv1.z + av.z * wv2.z + av.w * wv3.z;
                acc[r][3] += av.x * wv0.w + av.y * wv1.w + av.z * wv2.w + av.w * wv3.w;
            }
        }
        __syncthreads();
    }
#pragma unroll
    for (int r = 0; r < 8; r++) {
        int row = rbase + ty * 8 + r;
        if (row < NN) *(float4*)&C[(size_t)row * DD + 4 * tx] =
            make_float4(acc[r][0], acc[r][1], acc[r][2], acc[r][3]);
    }
}

// ---- CSR gather-aggregate: one wave per node, float2 per lane, no atomics ----
__global__ __launch_bounds__(256) void gather_kernel(const float* __restrict__ xw,
                                                     const int* __restrict__ rowptr,
                                                     const int* __restrict__ csr_src,
                                                     const float* __restrict__ csr_coef,
                                                     float* __restrict__ agg) {
    int wid = (int)((blockIdx.x * 256 + threadIdx.x) >> 6);
    int l = threadIdx.x & 63;
    if (wid >= NN) return;
    int beg = rowptr[wid], end = rowptr[wid + 1];
    float ax = 0.f, ay = 0.f;
    int i = beg;
    for (; i + 2 <= end; i += 2) {
        int s0 = csr_src[i], s1 = csr_src[i + 1];
        float c0 = csr_coef[i], c1 = csr_coef[i + 1];
        float2 x0 = ((const float2*)(xw + (size_t)s0 * DD))[l];
        float2 x1 = ((const float2*)(xw + (size_t)s1 * DD))[l];
        ax += x0.x * c0 + x1.x * c1;
        ay += x0.y * c0 + x1.y * c1;
    }
    if (i < end) {
        int s0 = csr_src[i];
        float c0 = csr_coef[i];
        float2 x0 = ((const float2*)(xw + (size_t)s0 * DD))[l];
        ax += x0.x * c0;
        ay += x0.y * c0;
    }
    ((float2*)(agg + (size_t)wid * DD))[l] = make_float2(ax, ay);
}

// ---- batchnorm stats: sums[0..127]=sum, sums[128..255]=sumsq ----
__global__ __launch_bounds__(256) void bnstat_kernel(const float* __restrict__ h, float* __restrict__ sums) {
    int d = threadIdx.x & 127;
    int rg = threadIdx.x >> 7;
    int r0 = blockIdx.x * 256 + rg;
    float s = 0.f, q = 0.f;
    for (int i = 0; i < 128; i++) {
        int r = r0 + 2 * i;
        if (r < NN) {
            float v = h[(size_t)r * DD + d];
            s += v;
            q += v * v;
        }
    }
    __shared__ float ls[256], lq[256];
    ls[threadIdx.x] = s;
    lq[threadIdx.x] = q;
    __syncthreads();
    if (threadIdx.x < 128) {
        s = ls[threadIdx.x] + ls[threadIdx.x + 128];
        q = lq[threadIdx.x] + lq[threadIdx.x + 128];
        atomicAdd(&sums[d], s);
        atomicAdd(&sums[128 + d], q);
    }
}

// ---- fold sums -> per-feature scale/shift: scale=g*rsqrt(var+eps), shift=be-mu*scale ----
__global__ __launch_bounds__(128) void bnfin_kernel(const float* __restrict__ sums,
                                                    const float* __restrict__ g,
                                                    const float* __restrict__ be,
                                                    float* __restrict__ normp) {
    int d = threadIdx.x;
    const float invN = 1.0f / (float)NN;
    float mu = sums[d] * invN;
    float var = sums[128 + d] * invN - mu * mu;
    float sc = rsqrtf(var + 1e-5f) * g[d];
    normp[d] = sc;
    normp[128 + d] = be[d] - mu * sc;
}

// ---- final normalize + affine (no act), writes d_out. GCN bias b omitted: cancels in BN. ----
__global__ __launch_bounds__(256) void bnapply_kernel(const float* __restrict__ h,
                                                      const float* __restrict__ sums,
                                                      const float* __restrict__ g,
                                                      const float* __restrict__ be,
                                                      float* __restrict__ out) {
    int idx = blockIdx.x * 256 + threadIdx.x;
    if (idx >= NN * DD) return;
    int d = idx & 127;
    const float invN = 1.0f / (float)NN;
    float mu = sums[d] * invN;
    float var = sums[128 + d] * invN - mu * mu;
    float inv = rsqrtf(var + 1e-5f);
    out[idx] = (h[idx] - mu) * inv * g[d] + be[d];
}

extern "C" void kernel_launch(void* const* d_in, const int* in_sizes, int n_in,
                              void* d_out, int out_size, void* d_ws, size_t ws_size,
                              hipStream_t stream) {
    const float* x = (const float*)d_in[0];
    const int* ei = (const int*)d_in[1];
    const int* srcp = ei;
    const int* dstp = ei + NE;
    const float* w[3]  = {(const float*)d_in[2], (const float*)d_in[6],  (const float*)d_in[10]};
    const float* g[3]  = {(const float*)d_in[4], (const float*)d_in[8],  (const float*)d_in[12]};
    const float* be[3] = {(const float*)d_in[5], (const float*)d_in[9],  (const float*)d_in[13]};

    // workspace layout (~68 MB)
    float* bufA = (float*)d_ws;                        // xw  [NN*DD]
    float* bufB = bufA + (size_t)NN * DD;              // h / agg [NN*DD]
    int* deg    = (int*)(bufB + (size_t)NN * DD);      // [NN]
    int* cursor = deg + NN;                            // [NN]  (adjacent: one memset)
    int* rowptr = cursor + NN;                         // [NN+1]
    float* dinv = (float*)(rowptr + NN + 1);           // [NN]
    float* sums = dinv + NN;                           // [3*256]
    float* ss   = sums + 3 * 256;                      // [2*256] scale/shift L0,L1
    int* partials = (int*)(ss + 2 * 256);              // [256]
    int* blockoff = partials + 256;                    // [256]
    int* csr_src = blockoff + 256;                     // [NTOT]
    float* csr_coef = (float*)(csr_src + NTOT);        // [NTOT]
    float* out = (float*)d_out;

    // ---- CSR build (once; edge_index constant across layers) ----
    hipMemsetAsync(deg, 0, 2 * NN * sizeof(int), stream);        // deg + cursor
    hipMemsetAsync(sums, 0, 3 * 256 * sizeof(float), stream);    // all layers' stats
    deg_kernel<<<(NE + 255) / 256, 256, 0, stream>>>(dstp, deg);
    dinv_kernel<<<(NN + 255) / 256, 256, 0, stream>>>(deg, dinv);
    scanA_kernel<<<NB, 256, 0, stream>>>(deg, partials);
    scanB_kernel<<<1, 256, 0, stream>>>(partials, blockoff, rowptr);
    scanC_kernel<<<NB, 256, 0, stream>>>(deg, blockoff, rowptr);
    fill_kernel<<<(NTOT + 255) / 256, 256, 0, stream>>>(srcp, dstp, rowptr, cursor, dinv, csr_src, csr_coef);

    for (int L = 0; L < 3; ++L) {
        const float* in = (L == 0) ? x : bufB;
        const float* normp = (L == 0) ? nullptr : (ss + (L - 1) * 256);
        gemm_kernel<<<(NN + 63) / 64, 256, 0, stream>>>(in, w[L], normp, bufA);
        gather_kernel<<<(NN + 3) / 4, 256, 0, stream>>>(bufA, rowptr, csr_src, csr_coef, bufB);
        bnstat_kernel<<<(NN + 255) / 256, 256, 0, stream>>>(bufB, sums + L * 256);
        if (L < 2) {
            bnfin_kernel<<<1, 128, 0, stream>>>(sums + L * 256, g[L], be[L], ss + L * 256);
        } else {
            bnapply_kernel<<<(NN * DD + 255) / 256, 256, 0, stream>>>(bufB, sums + L * 256, g[L], be[L], out);
        }
    }
}

// Round 6
// 483.211 us; speedup vs baseline: 3.0299x; 1.3704x over previous
//
#include <hip/hip_runtime.h>
#include <hip/hip_bf16.h>

#define NN 60000
#define NE 600000
#define DD 128
#define NTOT (NE + NN)
#define NB ((NN + 255) / 256)   // 235 blocks for scan

typedef __attribute__((ext_vector_type(8))) short short8;
typedef __attribute__((ext_vector_type(4))) float f32x4;

__device__ __forceinline__ unsigned short f2bf(float f) {
    unsigned int u = __float_as_uint(f);
    unsigned int r = (u + 0x7FFF + ((u >> 16) & 1)) >> 16;  // RNE
    return (unsigned short)r;
}
__device__ __forceinline__ float bflo(unsigned int u) { return __uint_as_float(u << 16); }
__device__ __forceinline__ float bfhi(unsigned int u) { return __uint_as_float(u & 0xFFFF0000u); }

// ---- degree (edges only; +1 self-loop folded in later) ----
__global__ __launch_bounds__(256) void deg_kernel(const int* __restrict__ dst, int* __restrict__ deg) {
    int e = blockIdx.x * 256 + threadIdx.x;
    if (e < NE) atomicAdd(&deg[dst[e]], 1);
}

__global__ __launch_bounds__(256) void dinv_kernel(const int* __restrict__ deg, float* __restrict__ dinv) {
    int i = blockIdx.x * 256 + threadIdx.x;
    if (i < NN) dinv[i] = rsqrtf((float)(deg[i] + 1));
}

// ---- 3-phase coalesced exclusive scan of (deg[i]+1) -> rowptr ----
__global__ __launch_bounds__(256) void scanA_kernel(const int* __restrict__ deg, int* __restrict__ partials) {
    __shared__ int lds[256];
    int i = blockIdx.x * 256 + threadIdx.x;
    int v = (i < NN) ? deg[i] + 1 : 0;
    lds[threadIdx.x] = v;
    __syncthreads();
    for (int off = 128; off > 0; off >>= 1) {
        if (threadIdx.x < off) lds[threadIdx.x] += lds[threadIdx.x + off];
        __syncthreads();
    }
    if (threadIdx.x == 0) partials[blockIdx.x] = lds[0];
}

__global__ __launch_bounds__(256) void scanB_kernel(const int* __restrict__ partials,
                                                    int* __restrict__ blockoff,
                                                    int* __restrict__ rowptr) {
    __shared__ int lds[256];
    int t = threadIdx.x;
    int v = (t < NB) ? partials[t] : 0;
    lds[t] = v;
    __syncthreads();
    for (int off = 1; off < 256; off <<= 1) {
        int u = (t >= off) ? lds[t - off] : 0;
        __syncthreads();
        lds[t] += u;
        __syncthreads();
    }
    if (t < NB) blockoff[t] = lds[t] - v;  // exclusive
    if (t == 0) rowptr[NN] = NTOT;
}

__global__ __launch_bounds__(256) void scanC_kernel(const int* __restrict__ deg,
                                                    const int* __restrict__ blockoff,
                                                    int* __restrict__ rowptr) {
    __shared__ int lds[256];
    int i = blockIdx.x * 256 + threadIdx.x;
    int t = threadIdx.x;
    int v = (i < NN) ? deg[i] + 1 : 0;
    lds[t] = v;
    __syncthreads();
    for (int off = 1; off < 256; off <<= 1) {
        int u = (t >= off) ? lds[t - off] : 0;
        __syncthreads();
        lds[t] += u;
        __syncthreads();
    }
    if (i < NN) rowptr[i] = blockoff[blockIdx.x] + lds[t] - v;
}

// ---- CSR fill: items [0,NE) real edges, [NE,NTOT) self-loops ----
__global__ __launch_bounds__(256) void fill_kernel(const int* __restrict__ src, const int* __restrict__ dst,
                                                   const int* __restrict__ rowptr, int* __restrict__ cursor,
                                                   const float* __restrict__ dinv,
                                                   int* __restrict__ csr_src, float* __restrict__ csr_coef) {
    int e = blockIdx.x * 256 + threadIdx.x;
    if (e >= NTOT) return;
    int s, t;
    if (e < NE) { s = src[e]; t = dst[e]; }
    else { s = t = e - NE; }
    int pos = atomicAdd(&cursor[t], 1);
    int i = rowptr[t] + pos;
    csr_src[i] = s;
    csr_coef[i] = dinv[s] * dinv[t];
}

// ---- W convert+transpose: Wt[n][k] bf16 <- W[k][n] fp32 ----
__global__ __launch_bounds__(256) void wcvt_kernel(const float* __restrict__ W, unsigned short* __restrict__ Wt) {
    int idx = blockIdx.x * 256 + threadIdx.x;  // 8192 items, grid 32
    if (idx >= 64 * DD) return;
    int k2 = (idx >> 7) * 2;
    int n = idx & 127;
    unsigned int b0 = f2bf(W[k2 * DD + n]);
    unsigned int b1 = f2bf(W[(k2 + 1) * DD + n]);
    ((unsigned int*)Wt)[(n * DD + k2) >> 1] = b0 | (b1 << 16);
}

// ---- MFMA GEMM: C_bf16[NN x 128] = f(A_fp32) @ W, f = fused BN+LeakyReLU (or identity) ----
// One wave per 16 rows; 8 col-tiles of 16; K=128 in 4 chunks of 32.
// Layouts (m89/m120-verified): A/B frag: own=lane&15, k=(lane>>4)*8+j; C/D: col=lane&15,row=(lane>>4)*4+reg.
// NOTE: no waves/EU hint — (256,4) caused 64-VGPR cap + acc spill (R3: 1 GiB traffic).
__global__ __launch_bounds__(256) void gemm_mfma_kernel(const float* __restrict__ A,
                                                        const unsigned short* __restrict__ Wt,
                                                        const float* __restrict__ normp,
                                                        unsigned short* __restrict__ C) {
    __shared__ float lds[4][16][132];  // 33 KB, per-wave repack tiles
    int tid = threadIdx.x;
    int wslot = tid >> 6;
    int wrow0 = (blockIdx.x * 4 + wslot) * 16;
    if (wrow0 >= NN) return;
    int l = tid & 63;
    int m = l & 15;
    int q = l >> 4;

    f32x4 acc[8];
#pragma unroll
    for (int i = 0; i < 8; i++) acc[i] = (f32x4){0.f, 0.f, 0.f, 0.f};

    const float* arow = A + (size_t)(wrow0 + m) * DD;
#pragma unroll
    for (int kc = 0; kc < 4; kc++) {
        int k0 = kc * 32 + q * 8;
        float4 a0 = *(const float4*)(arow + k0);
        float4 a1 = *(const float4*)(arow + k0 + 4);
        if (normp) {
            float4 sc0 = *(const float4*)(normp + k0);
            float4 sc1 = *(const float4*)(normp + k0 + 4);
            float4 sh0 = *(const float4*)(normp + 128 + k0);
            float4 sh1 = *(const float4*)(normp + 128 + k0 + 4);
            a0.x = fmaf(a0.x, sc0.x, sh0.x); a0.y = fmaf(a0.y, sc0.y, sh0.y);
            a0.z = fmaf(a0.z, sc0.z, sh0.z); a0.w = fmaf(a0.w, sc0.w, sh0.w);
            a1.x = fmaf(a1.x, sc1.x, sh1.x); a1.y = fmaf(a1.y, sc1.y, sh1.y);
            a1.z = fmaf(a1.z, sc1.z, sh1.z); a1.w = fmaf(a1.w, sc1.w, sh1.w);
            a0.x = (a0.x >= 0.f) ? a0.x : 0.01f * a0.x;
            a0.y = (a0.y >= 0.f) ? a0.y : 0.01f * a0.y;
            a0.z = (a0.z >= 0.f) ? a0.z : 0.01f * a0.z;
            a0.w = (a0.w >= 0.f) ? a0.w : 0.01f * a0.w;
            a1.x = (a1.x >= 0.f) ? a1.x : 0.01f * a1.x;
            a1.y = (a1.y >= 0.f) ? a1.y : 0.01f * a1.y;
            a1.z = (a1.z >= 0.f) ? a1.z : 0.01f * a1.z;
            a1.w = (a1.w >= 0.f) ? a1.w : 0.01f * a1.w;
        }
        short8 af;
        af[0] = (short)f2bf(a0.x); af[1] = (short)f2bf(a0.y);
        af[2] = (short)f2bf(a0.z); af[3] = (short)f2bf(a0.w);
        af[4] = (short)f2bf(a1.x); af[5] = (short)f2bf(a1.y);
        af[6] = (short)f2bf(a1.z); af[7] = (short)f2bf(a1.w);
#pragma unroll
        for (int nt = 0; nt < 8; nt++) {
            short8 bf = *(const short8*)(Wt + (size_t)(nt * 16 + m) * DD + k0);
            acc[nt] = __builtin_amdgcn_mfma_f32_16x16x32_bf16(af, bf, acc[nt], 0, 0, 0);
        }
    }

    // epilogue: repack through per-wave LDS tile (wave-internal, no barrier needed)
    float (*tile)[132] = lds[wslot];
#pragma unroll
    for (int nt = 0; nt < 8; nt++)
#pragma unroll
        for (int r = 0; r < 4; r++)
            tile[q * 4 + r][nt * 16 + m] = acc[nt][r];

    unsigned short* crow = C + (size_t)(wrow0 + m) * DD;
#pragma unroll
    for (int j = 0; j < 8; j++) {
        int col = q * 4 + 16 * j;
        float4 v = *(float4*)&tile[m][col];
        unsigned int lo = f2bf(v.x) | ((unsigned int)f2bf(v.y) << 16);
        unsigned int hi = f2bf(v.z) | ((unsigned int)f2bf(v.w) << 16);
        uint2 p; p.x = lo; p.y = hi;
        *(uint2*)(crow + col) = p;  // 8 B aligned
    }
}

// ---- CSR gather-aggregate: one wave per node, bf16 xw, 2 features per lane ----
__global__ __launch_bounds__(256) void gather_kernel(const unsigned short* __restrict__ xw,
                                                     const int* __restrict__ rowptr,
                                                     const int* __restrict__ csr_src,
                                                     const float* __restrict__ csr_coef,
                                                     float* __restrict__ agg) {
    int wid = (int)((blockIdx.x * 256 + threadIdx.x) >> 6);
    int l = threadIdx.x & 63;
    if (wid >= NN) return;
    int beg = rowptr[wid], end = rowptr[wid + 1];
    float ax = 0.f, ay = 0.f;
    int i = beg;
    for (; i + 4 <= end; i += 4) {
        int s0 = csr_src[i], s1 = csr_src[i + 1], s2 = csr_src[i + 2], s3 = csr_src[i + 3];
        float c0 = csr_coef[i], c1 = csr_coef[i + 1], c2 = csr_coef[i + 2], c3 = csr_coef[i + 3];
        unsigned int u0 = *(const unsigned int*)(xw + (size_t)s0 * DD + 2 * l);
        unsigned int u1 = *(const unsigned int*)(xw + (size_t)s1 * DD + 2 * l);
        unsigned int u2 = *(const unsigned int*)(xw + (size_t)s2 * DD + 2 * l);
        unsigned int u3 = *(const unsigned int*)(xw + (size_t)s3 * DD + 2 * l);
        ax += bflo(u0) * c0 + bflo(u1) * c1 + bflo(u2) * c2 + bflo(u3) * c3;
        ay += bfhi(u0) * c0 + bfhi(u1) * c1 + bfhi(u2) * c2 + bfhi(u3) * c3;
    }
    for (; i < end; i++) {
        int s0 = csr_src[i];
        float c0 = csr_coef[i];
        unsigned int u0 = *(const unsigned int*)(xw + (size_t)s0 * DD + 2 * l);
        ax += bflo(u0) * c0;
        ay += bfhi(u0) * c0;
    }
    ((float2*)(agg + (size_t)wid * DD))[l] = make_float2(ax, ay);
}

// ---- batchnorm stats: sums[0..127]=sum, sums[128..255]=sumsq ----
__global__ __launch_bounds__(256) void bnstat_kernel(const float* __restrict__ h, float* __restrict__ sums) {
    int d = threadIdx.x & 127;
    int rg = threadIdx.x >> 7;
    int r0 = blockIdx.x * 256 + rg;
    float s = 0.f, q = 0.f;
    for (int i = 0; i < 128; i++) {
        int r = r0 + 2 * i;
        if (r < NN) {
            float v = h[(size_t)r * DD + d];
            s += v;
            q += v * v;
        }
    }
    __shared__ float ls[256], lq[256];
    ls[threadIdx.x] = s;
    lq[threadIdx.x] = q;
    __syncthreads();
    if (threadIdx.x < 128) {
        s = ls[threadIdx.x] + ls[threadIdx.x + 128];
        q = lq[threadIdx.x] + lq[threadIdx.x + 128];
        atomicAdd(&sums[d], s);
        atomicAdd(&sums[128 + d], q);
    }
}

// ---- fold sums -> scale/shift: scale=g*rsqrt(var+eps), shift=be-mu*scale ----
__global__ __launch_bounds__(128) void bnfin_kernel(const float* __restrict__ sums,
                                                    const float* __restrict__ g,
                                                    const float* __restrict__ be,
                                                    float* __restrict__ normp) {
    int d = threadIdx.x;
    const float invN = 1.0f / (float)NN;
    float mu = sums[d] * invN;
    float var = sums[128 + d] * invN - mu * mu;
    float sc = rsqrtf(var + 1e-5f) * g[d];
    normp[d] = sc;
    normp[128 + d] = be[d] - mu * sc;
}

// ---- final normalize + affine, float4, writes d_out. GCN bias b omitted: cancels in BN. ----
__global__ __launch_bounds__(256) void bnapply_kernel(const float* __restrict__ h,
                                                      const float* __restrict__ sums,
                                                      const float* __restrict__ g,
                                                      const float* __restrict__ be,
                                                      float* __restrict__ out) {
    int idx = blockIdx.x * 256 + threadIdx.x;
    if (idx >= NN * DD / 4) return;
    int d = (idx * 4) & 127;
    const float invN = 1.0f / (float)NN;
    float4 s4 = *(const float4*)&sums[d];
    float4 q4 = *(const float4*)&sums[128 + d];
    float4 g4 = *(const float4*)&g[d];
    float4 b4 = *(const float4*)&be[d];
    float4 h4 = *(const float4*)&h[idx * 4];
    float mu, inv;
    float4 o;
    mu = s4.x * invN; inv = rsqrtf(q4.x * invN - mu * mu + 1e-5f); o.x = (h4.x - mu) * inv * g4.x + b4.x;
    mu = s4.y * invN; inv = rsqrtf(q4.y * invN - mu * mu + 1e-5f); o.y = (h4.y - mu) * inv * g4.y + b4.y;
    mu = s4.z * invN; inv = rsqrtf(q4.z * invN - mu * mu + 1e-5f); o.z = (h4.z - mu) * inv * g4.z + b4.z;
    mu = s4.w * invN; inv = rsqrtf(q4.w * invN - mu * mu + 1e-5f); o.w = (h4.w - mu) * inv * g4.w + b4.w;
    *(float4*)&out[idx * 4] = o;
}

extern "C" void kernel_launch(void* const* d_in, const int* in_sizes, int n_in,
                              void* d_out, int out_size, void* d_ws, size_t ws_size,
                              hipStream_t stream) {
    const float* x = (const float*)d_in[0];
    const int* ei = (const int*)d_in[1];
    const int* srcp = ei;
    const int* dstp = ei + NE;
    const float* w[3]  = {(const float*)d_in[2], (const float*)d_in[6],  (const float*)d_in[10]};
    const float* g[3]  = {(const float*)d_in[4], (const float*)d_in[8],  (const float*)d_in[12]};
    const float* be[3] = {(const float*)d_in[5], (const float*)d_in[9],  (const float*)d_in[13]};

    // workspace layout (~53 MB), all chunks 16-B aligned
    unsigned short* xwb = (unsigned short*)d_ws;        // bf16 xw [NN*DD]
    float* bufB = (float*)(xwb + (size_t)NN * DD);      // agg fp32 [NN*DD]
    int* deg    = (int*)(bufB + (size_t)NN * DD);       // [NN]
    int* cursor = deg + NN;                             // [NN]
    int* rowptr = cursor + NN;                          // [NN+16] (padded for alignment)
    float* dinv = (float*)(rowptr + NN + 16);           // [NN]
    float* sums = dinv + NN;                            // [3*256]
    float* ss   = sums + 3 * 256;                       // [2*256] scale/shift L0,L1
    int* partials = (int*)(ss + 2 * 256);               // [256]
    int* blockoff = partials + 256;                     // [256]
    unsigned short* Wt = (unsigned short*)(blockoff + 256);  // [3*128*128] bf16
    int* csr_src = (int*)(Wt + 3 * DD * DD);            // [NTOT]
    float* csr_coef = (float*)(csr_src + NTOT);         // [NTOT]
    float* out = (float*)d_out;

    // ---- CSR build (once; edge_index constant across layers) ----
    hipMemsetAsync(deg, 0, 2 * NN * sizeof(int), stream);        // deg + cursor
    hipMemsetAsync(sums, 0, 3 * 256 * sizeof(float), stream);    // all layers' stats
    deg_kernel<<<(NE + 255) / 256, 256, 0, stream>>>(dstp, deg);
    dinv_kernel<<<(NN + 255) / 256, 256, 0, stream>>>(deg, dinv);
    scanA_kernel<<<NB, 256, 0, stream>>>(deg, partials);
    scanB_kernel<<<1, 256, 0, stream>>>(partials, blockoff, rowptr);
    scanC_kernel<<<NB, 256, 0, stream>>>(deg, blockoff, rowptr);
    fill_kernel<<<(NTOT + 255) / 256, 256, 0, stream>>>(srcp, dstp, rowptr, cursor, dinv, csr_src, csr_coef);
    for (int L = 0; L < 3; ++L)
        wcvt_kernel<<<32, 256, 0, stream>>>(w[L], Wt + L * DD * DD);

    const int GEMM_GRID = (NN / 16 + 3) / 4;  // 938
    for (int L = 0; L < 3; ++L) {
        const float* in = (L == 0) ? x : bufB;
        const float* normp = (L == 0) ? nullptr : (ss + (L - 1) * 256);
        gemm_mfma_kernel<<<GEMM_GRID, 256, 0, stream>>>(in, Wt + L * DD * DD, normp, xwb);
        gather_kernel<<<(NN + 3) / 4, 256, 0, stream>>>(xwb, rowptr, csr_src, csr_coef, bufB);
        bnstat_kernel<<<(NN + 255) / 256, 256, 0, stream>>>(bufB, sums + L * 256);
        if (L < 2) {
            bnfin_kernel<<<1, 128, 0, stream>>>(sums + L * 256, g[L], be[L], ss + L * 256);
        } else {
            bnapply_kernel<<<(NN * DD / 4 + 255) / 256, 256, 0, stream>>>(bufB, sums + L * 256, g[L], be[L], out);
        }
    }
}

// Round 7
// 443.415 us; speedup vs baseline: 3.3019x; 1.0897x over previous
//
#include <hip/hip_runtime.h>
#include <hip/hip_bf16.h>

#define NN 60000
#define NE 600000
#define DD 128
#define NTOT (NE + NN)
#define NB ((NN + 255) / 256)   // 235 blocks for scan

typedef __attribute__((ext_vector_type(8))) short short8;
typedef __attribute__((ext_vector_type(4))) float f32x4;

__device__ __forceinline__ unsigned short f2bf(float f) {
    unsigned int u = __float_as_uint(f);
    unsigned int r = (u + 0x7FFF + ((u >> 16) & 1)) >> 16;  // RNE
    return (unsigned short)r;
}
__device__ __forceinline__ float bflo(unsigned int u) { return __uint_as_float(u << 16); }
__device__ __forceinline__ float bfhi(unsigned int u) { return __uint_as_float(u & 0xFFFF0000u); }

// ---- degree (edges only; +1 self-loop folded in later) ----
__global__ __launch_bounds__(256) void deg_kernel(const int* __restrict__ dst, int* __restrict__ deg) {
    int e = blockIdx.x * 256 + threadIdx.x;
    if (e < NE) atomicAdd(&deg[dst[e]], 1);
}

// ---- scanA: per-block sums of (deg+1), fused dinv ----
__global__ __launch_bounds__(256) void scanA_kernel(const int* __restrict__ deg, int* __restrict__ partials,
                                                    float* __restrict__ dinv) {
    __shared__ int lds[256];
    int i = blockIdx.x * 256 + threadIdx.x;
    int dv = (i < NN) ? deg[i] : 0;
    if (i < NN) dinv[i] = rsqrtf((float)(dv + 1));
    int v = (i < NN) ? dv + 1 : 0;
    lds[threadIdx.x] = v;
    __syncthreads();
    for (int off = 128; off > 0; off >>= 1) {
        if (threadIdx.x < off) lds[threadIdx.x] += lds[threadIdx.x + off];
        __syncthreads();
    }
    if (threadIdx.x == 0) partials[blockIdx.x] = lds[0];
}

__global__ __launch_bounds__(256) void scanB_kernel(const int* __restrict__ partials,
                                                    int* __restrict__ blockoff,
                                                    int* __restrict__ rowptr) {
    __shared__ int lds[256];
    int t = threadIdx.x;
    int v = (t < NB) ? partials[t] : 0;
    lds[t] = v;
    __syncthreads();
    for (int off = 1; off < 256; off <<= 1) {
        int u = (t >= off) ? lds[t - off] : 0;
        __syncthreads();
        lds[t] += u;
        __syncthreads();
    }
    if (t < NB) blockoff[t] = lds[t] - v;  // exclusive
    if (t == 0) rowptr[NN] = NTOT;
}

__global__ __launch_bounds__(256) void scanC_kernel(const int* __restrict__ deg,
                                                    const int* __restrict__ blockoff,
                                                    int* __restrict__ rowptr) {
    __shared__ int lds[256];
    int i = blockIdx.x * 256 + threadIdx.x;
    int t = threadIdx.x;
    int v = (i < NN) ? deg[i] + 1 : 0;
    lds[t] = v;
    __syncthreads();
    for (int off = 1; off < 256; off <<= 1) {
        int u = (t >= off) ? lds[t - off] : 0;
        __syncthreads();
        lds[t] += u;
        __syncthreads();
    }
    if (i < NN) rowptr[i] = blockoff[blockIdx.x] + lds[t] - v;
}

// ---- CSR fill: packed int2{src, coef_bits} -> ONE 8B scattered store per edge ----
__global__ __launch_bounds__(256) void fill_kernel(const int* __restrict__ src, const int* __restrict__ dst,
                                                   const int* __restrict__ rowptr, int* __restrict__ cursor,
                                                   const float* __restrict__ dinv,
                                                   int2* __restrict__ csr) {
    int e = blockIdx.x * 256 + threadIdx.x;
    if (e >= NTOT) return;
    int s, t;
    if (e < NE) { s = src[e]; t = dst[e]; }
    else { s = t = e - NE; }
    int pos = atomicAdd(&cursor[t], 1);
    int2 rec;
    rec.x = s;
    rec.y = __float_as_int(dinv[s] * dinv[t]);
    csr[rowptr[t] + pos] = rec;
}

// ---- W convert+transpose, all 3 layers: Wt[L][n][k] bf16 <- W_L[k][n] fp32 ----
__global__ __launch_bounds__(256) void wcvt_kernel(const float* __restrict__ W0, const float* __restrict__ W1,
                                                   const float* __restrict__ W2, unsigned short* __restrict__ Wt) {
    int idx = blockIdx.x * 256 + threadIdx.x;  // 3*64*128 items
    if (idx >= 3 * 64 * DD) return;
    int L = idx / (64 * DD);
    int r = idx - L * 64 * DD;
    const float* W = (L == 0) ? W0 : (L == 1) ? W1 : W2;
    int k2 = (r >> 7) * 2;
    int n = r & 127;
    unsigned int b0 = f2bf(W[k2 * DD + n]);
    unsigned int b1 = f2bf(W[(k2 + 1) * DD + n]);
    ((unsigned int*)Wt)[(L * DD * DD + n * DD + k2) >> 1] = b0 | (b1 << 16);
}

// ---- MFMA GEMM: C_bf16[NN x 128] = f(A) @ W ----
// BF16IN: A is bf16 (layers 1,2; normp applied); else fp32 (layer 0, normp null).
// One wave per 16 rows; 8 col-tiles of 16; K=128 in 4 chunks of 32.
// Layouts (m89/m120): A/B frag own=lane&15,k=(lane>>4)*8+j; C/D col=lane&15,row=(lane>>4)*4+reg.
// NOTE: no waves/EU hint — (256,4) caused 64-VGPR cap + acc spill (R3: 1 GiB traffic).
template <bool BF16IN>
__global__ __launch_bounds__(256) void gemm_mfma_kernel(const void* __restrict__ Ain,
                                                        const unsigned short* __restrict__ Wt,
                                                        const float* __restrict__ normp,
                                                        unsigned short* __restrict__ C) {
    __shared__ float lds[4][16][132];  // 33 KB, per-wave repack tiles
    int tid = threadIdx.x;
    int wslot = tid >> 6;
    int wrow0 = (blockIdx.x * 4 + wslot) * 16;
    if (wrow0 >= NN) return;
    int l = tid & 63;
    int m = l & 15;
    int q = l >> 4;

    f32x4 acc[8];
#pragma unroll
    for (int i = 0; i < 8; i++) acc[i] = (f32x4){0.f, 0.f, 0.f, 0.f};

#pragma unroll
    for (int kc = 0; kc < 4; kc++) {
        int k0 = kc * 32 + q * 8;
        float a[8];
        if (BF16IN) {
            const unsigned short* arow = (const unsigned short*)Ain + (size_t)(wrow0 + m) * DD;
            uint4 u = *(const uint4*)(arow + k0);
            a[0] = bflo(u.x); a[1] = bfhi(u.x); a[2] = bflo(u.y); a[3] = bfhi(u.y);
            a[4] = bflo(u.z); a[5] = bfhi(u.z); a[6] = bflo(u.w); a[7] = bfhi(u.w);
        } else {
            const float* arow = (const float*)Ain + (size_t)(wrow0 + m) * DD;
            float4 a0 = *(const float4*)(arow + k0);
            float4 a1 = *(const float4*)(arow + k0 + 4);
            a[0] = a0.x; a[1] = a0.y; a[2] = a0.z; a[3] = a0.w;
            a[4] = a1.x; a[5] = a1.y; a[6] = a1.z; a[7] = a1.w;
        }
        if (normp) {
#pragma unroll
            for (int j = 0; j < 8; j++) {
                float v = fmaf(a[j], normp[k0 + j], normp[128 + k0 + j]);
                a[j] = (v >= 0.f) ? v : 0.01f * v;
            }
        }
        short8 af;
#pragma unroll
        for (int j = 0; j < 8; j++) af[j] = (short)f2bf(a[j]);
#pragma unroll
        for (int nt = 0; nt < 8; nt++) {
            short8 bf = *(const short8*)(Wt + (size_t)(nt * 16 + m) * DD + k0);
            acc[nt] = __builtin_amdgcn_mfma_f32_16x16x32_bf16(af, bf, acc[nt], 0, 0, 0);
        }
    }

    // epilogue: repack through per-wave LDS tile (wave-internal, no barrier needed)
    float (*tile)[132] = lds[wslot];
#pragma unroll
    for (int nt = 0; nt < 8; nt++)
#pragma unroll
        for (int r = 0; r < 4; r++)
            tile[q * 4 + r][nt * 16 + m] = acc[nt][r];

    unsigned short* crow = C + (size_t)(wrow0 + m) * DD;
#pragma unroll
    for (int j = 0; j < 8; j++) {
        int col = q * 4 + 16 * j;
        float4 v = *(float4*)&tile[m][col];
        unsigned int lo = f2bf(v.x) | ((unsigned int)f2bf(v.y) << 16);
        unsigned int hi = f2bf(v.z) | ((unsigned int)f2bf(v.w) << 16);
        uint2 p; p.x = lo; p.y = hi;
        *(uint2*)(crow + col) = p;  // 8 B aligned
    }
}

// ---- CSR gather-aggregate: one wave per node, bf16 xw -> bf16 agg ----
__global__ __launch_bounds__(256) void gather_kernel(const unsigned short* __restrict__ xw,
                                                     const int* __restrict__ rowptr,
                                                     const int2* __restrict__ csr,
                                                     unsigned short* __restrict__ agg) {
    int wid = (int)((blockIdx.x * 256 + threadIdx.x) >> 6);
    int l = threadIdx.x & 63;
    if (wid >= NN) return;
    int beg = rowptr[wid], end = rowptr[wid + 1];
    float ax = 0.f, ay = 0.f;
    int i = beg;
    for (; i + 4 <= end; i += 4) {
        int2 r0 = csr[i], r1 = csr[i + 1], r2 = csr[i + 2], r3 = csr[i + 3];
        unsigned int u0 = *(const unsigned int*)(xw + (size_t)r0.x * DD + 2 * l);
        unsigned int u1 = *(const unsigned int*)(xw + (size_t)r1.x * DD + 2 * l);
        unsigned int u2 = *(const unsigned int*)(xw + (size_t)r2.x * DD + 2 * l);
        unsigned int u3 = *(const unsigned int*)(xw + (size_t)r3.x * DD + 2 * l);
        float c0 = __int_as_float(r0.y), c1 = __int_as_float(r1.y);
        float c2 = __int_as_float(r2.y), c3 = __int_as_float(r3.y);
        ax += bflo(u0) * c0 + bflo(u1) * c1 + bflo(u2) * c2 + bflo(u3) * c3;
        ay += bfhi(u0) * c0 + bfhi(u1) * c1 + bfhi(u2) * c2 + bfhi(u3) * c3;
    }
    for (; i < end; i++) {
        int2 r0 = csr[i];
        unsigned int u0 = *(const unsigned int*)(xw + (size_t)r0.x * DD + 2 * l);
        float c0 = __int_as_float(r0.y);
        ax += bflo(u0) * c0;
        ay += bfhi(u0) * c0;
    }
    ((unsigned int*)(agg + (size_t)wid * DD))[l] = (unsigned int)f2bf(ax) | ((unsigned int)f2bf(ay) << 16);
}

// ---- batchnorm stats on bf16 agg: sums[0..127]=sum, sums[128..255]=sumsq ----
// thread owns features (2d, 2d+1), 4 row-groups, 64 rows each; block covers 256 rows.
__global__ __launch_bounds__(256) void bnstat_kernel(const unsigned short* __restrict__ h, float* __restrict__ sums) {
    int d2 = threadIdx.x & 63;   // feature pair
    int rg = threadIdx.x >> 6;   // 0..3
    int r0 = blockIdx.x * 256 + rg;
    float s0 = 0.f, q0 = 0.f, s1 = 0.f, q1 = 0.f;
    for (int i = 0; i < 64; i++) {
        int r = r0 + 4 * i;
        if (r < NN) {
            unsigned int u = *(const unsigned int*)(h + (size_t)r * DD + 2 * d2);
            float v0 = bflo(u), v1 = bfhi(u);
            s0 += v0; q0 += v0 * v0;
            s1 += v1; q1 += v1 * v1;
        }
    }
    __shared__ float lds[256][4];
    lds[threadIdx.x][0] = s0; lds[threadIdx.x][1] = q0;
    lds[threadIdx.x][2] = s1; lds[threadIdx.x][3] = q1;
    __syncthreads();
    if (threadIdx.x < 128) {
#pragma unroll
        for (int j = 0; j < 4; j++) lds[threadIdx.x][j] += lds[threadIdx.x + 128][j];
    }
    __syncthreads();
    if (threadIdx.x < 64) {
        float a0 = lds[threadIdx.x][0] + lds[threadIdx.x + 64][0];
        float a1 = lds[threadIdx.x][1] + lds[threadIdx.x + 64][1];
        float a2 = lds[threadIdx.x][2] + lds[threadIdx.x + 64][2];
        float a3 = lds[threadIdx.x][3] + lds[threadIdx.x + 64][3];
        atomicAdd(&sums[2 * d2], a0);
        atomicAdd(&sums[128 + 2 * d2], a1);
        atomicAdd(&sums[2 * d2 + 1], a2);
        atomicAdd(&sums[128 + 2 * d2 + 1], a3);
    }
}

// ---- fold sums -> scale/shift: scale=g*rsqrt(var+eps), shift=be-mu*scale ----
__global__ __launch_bounds__(128) void bnfin_kernel(const float* __restrict__ sums,
                                                    const float* __restrict__ g,
                                                    const float* __restrict__ be,
                                                    float* __restrict__ normp) {
    int d = threadIdx.x;
    const float invN = 1.0f / (float)NN;
    float mu = sums[d] * invN;
    float var = sums[128 + d] * invN - mu * mu;
    float sc = rsqrtf(var + 1e-5f) * g[d];
    normp[d] = sc;
    normp[128 + d] = be[d] - mu * sc;
}

// ---- final: out_fp32 = bf16(agg)*scale+shift (normp precomputed by bnfin) ----
__global__ __launch_bounds__(256) void bnapply_kernel(const unsigned short* __restrict__ h,
                                                      const float* __restrict__ normp,
                                                      float* __restrict__ out) {
    int idx = blockIdx.x * 256 + threadIdx.x;  // one per 4 elements
    if (idx >= NN * DD / 4) return;
    int d = (idx * 4) & 127;
    uint2 u = *(const uint2*)(h + idx * 4);
    float4 sc = *(const float4*)&normp[d];
    float4 sh = *(const float4*)&normp[128 + d];
    float4 o;
    o.x = fmaf(bflo(u.x), sc.x, sh.x);
    o.y = fmaf(bfhi(u.x), sc.y, sh.y);
    o.z = fmaf(bflo(u.y), sc.z, sh.z);
    o.w = fmaf(bfhi(u.y), sc.w, sh.w);
    *(float4*)&out[idx * 4] = o;
}

extern "C" void kernel_launch(void* const* d_in, const int* in_sizes, int n_in,
                              void* d_out, int out_size, void* d_ws, size_t ws_size,
                              hipStream_t stream) {
    const float* x = (const float*)d_in[0];
    const int* ei = (const int*)d_in[1];
    const int* srcp = ei;
    const int* dstp = ei + NE;
    const float* w[3]  = {(const float*)d_in[2], (const float*)d_in[6],  (const float*)d_in[10]};
    const float* g[3]  = {(const float*)d_in[4], (const float*)d_in[8],  (const float*)d_in[12]};
    const float* be[3] = {(const float*)d_in[5], (const float*)d_in[9],  (const float*)d_in[13]};

    // workspace layout (~43 MB), all chunks 16-B aligned
    unsigned short* xwb  = (unsigned short*)d_ws;        // bf16 xw  [NN*DD]
    unsigned short* aggb = xwb + (size_t)NN * DD;        // bf16 agg [NN*DD]
    int* deg    = (int*)(aggb + (size_t)NN * DD);        // [NN]
    int* cursor = deg + NN;                              // [NN]
    int* rowptr = cursor + NN;                           // [NN+16]
    float* dinv = (float*)(rowptr + NN + 16);            // [NN]
    float* sums = dinv + NN;                             // [3*256]
    float* ss   = sums + 3 * 256;                        // [3*256] scale/shift per layer
    int* partials = (int*)(ss + 3 * 256);                // [256]
    int* blockoff = partials + 256;                      // [256]
    unsigned short* Wt = (unsigned short*)(blockoff + 256);  // [3*128*128] bf16
    int2* csr = (int2*)(Wt + 3 * DD * DD);               // [NTOT] packed {src, coef}
    float* out = (float*)d_out;

    // ---- CSR build (once; edge_index constant across layers) ----
    hipMemsetAsync(deg, 0, 2 * NN * sizeof(int), stream);        // deg + cursor
    hipMemsetAsync(sums, 0, 3 * 256 * sizeof(float), stream);    // all layers' stats
    deg_kernel<<<(NE + 255) / 256, 256, 0, stream>>>(dstp, deg);
    scanA_kernel<<<NB, 256, 0, stream>>>(deg, partials, dinv);
    scanB_kernel<<<1, 256, 0, stream>>>(partials, blockoff, rowptr);
    scanC_kernel<<<NB, 256, 0, stream>>>(deg, blockoff, rowptr);
    fill_kernel<<<(NTOT + 255) / 256, 256, 0, stream>>>(srcp, dstp, rowptr, cursor, dinv, csr);
    wcvt_kernel<<<(3 * 64 * DD + 255) / 256, 256, 0, stream>>>(w[0], w[1], w[2], Wt);

    const int GEMM_GRID = (NN / 16 + 3) / 4;  // 938
    for (int L = 0; L < 3; ++L) {
        const float* normp = (L == 0) ? nullptr : (ss + (L - 1) * 256);
        if (L == 0)
            gemm_mfma_kernel<false><<<GEMM_GRID, 256, 0, stream>>>(x, Wt, normp, xwb);
        else
            gemm_mfma_kernel<true><<<GEMM_GRID, 256, 0, stream>>>(aggb, Wt + L * DD * DD, normp, xwb);
        gather_kernel<<<(NN + 3) / 4, 256, 0, stream>>>(xwb, rowptr, csr, aggb);
        bnstat_kernel<<<(NN + 255) / 256, 256, 0, stream>>>(aggb, sums + L * 256);
        bnfin_kernel<<<1, 128, 0, stream>>>(sums + L * 256, g[L], be[L], ss + L * 256);
        if (L == 2)
            bnapply_kernel<<<(NN * DD / 4 + 255) / 256, 256, 0, stream>>>(aggb, ss + L * 256, out);
    }
}